// Round 3
// baseline (630.356 us; speedup 1.0000x reference)
//
#include <hip/hip_runtime.h>
#include <stdint.h>

#define QEPS 1e-8f

typedef __bf16 bf16x8 __attribute__((ext_vector_type(8)));
typedef unsigned short ushortx8 __attribute__((ext_vector_type(8)));
typedef float floatx4 __attribute__((ext_vector_type(4)));

// s (in d_ws): [0]=absmax bits of x, [1]=absmax bits of W, [2]=absmax of conv accum (quant units)
// ws layout (single-pass path): [0..16) s, [256..) y16 = int16 accum, [3552 rows][128 oc][224 ow]

__global__ void k_init(unsigned int* s) { if (threadIdx.x < 4) s[threadIdx.x] = 0u; }

__global__ __launch_bounds__(256) void k_absmax(
    const float4* __restrict__ x, int n4,
    const float* __restrict__ W, int nw,
    unsigned int* __restrict__ s) {
  __shared__ unsigned int red[256];
  const int t = threadIdx.x;
  unsigned int m = 0u;
  const int i = blockIdx.x * 256 + t;
  if (i < n4) {
    float4 v = x[i];
    m =        __float_as_uint(v.x) & 0x7fffffffu;
    m = max(m, __float_as_uint(v.y) & 0x7fffffffu);
    m = max(m, __float_as_uint(v.z) & 0x7fffffffu);
    m = max(m, __float_as_uint(v.w) & 0x7fffffffu);
  }
  red[t] = m;
  __syncthreads();
  for (int off = 128; off > 0; off >>= 1) {
    if (t < off) red[t] = max(red[t], red[t + off]);
    __syncthreads();
  }
  if (t == 0) atomicMax(&s[0], red[0]);

  if (blockIdx.x == 0) {
    unsigned int mw = 0u;
    for (int j = t; j < nw; j += 256)
      mw = max(mw, __float_as_uint(W[j]) & 0x7fffffffu);
    __syncthreads();
    red[t] = mw;
    __syncthreads();
    for (int off = 128; off > 0; off >>= 1) {
      if (t < off) red[t] = max(red[t], red[t + off]);
      __syncthreads();
    }
    if (t == 0) atomicMax(&s[1], red[0]);
  }
}

// ================= single-pass path: conv -> int16 ws, then streaming finalize =========
// MFMA conv (swapped operands): D = X * W^T -> reg r = ow (4 consecutive), lane col = oc.
// |acc + qb| <= 27*127*7 + ~16 < 2^15 -> int16 exact. Store y16[row][oc][ow(224)] + vmax.
__global__ __launch_bounds__(256) void k_conv_ws(
    const float* __restrict__ x, const float* __restrict__ W,
    const float* __restrict__ b, unsigned short* __restrict__ y16,
    unsigned int* __restrict__ s) {
  __shared__ __align__(16) unsigned short wl[32 * 130];  // [k][oc], pad 130
  __shared__ __align__(16) unsigned short xl[19 * 228];  // [slab*9+row][col], zero-row 18
  __shared__ __align__(16) float qbl[128];
  __shared__ float redf[256];

  const int t = threadIdx.x;
  const float s_in = fmaxf(__uint_as_float(s[0]) / 127.0f, QEPS);
  const float s_w  = fmaxf(__uint_as_float(s[1]) / 7.0f,  QEPS);
  const float s_b  = s_in * s_w;

  // stage quantized W (bf16 bits)
  for (int i = t; i < 3456; i += 256) {
    const int o = i / 27;
    const int k = i - o * 27;
    float q = rintf(W[i] / s_w);
    q = fminf(fmaxf(q, -7.0f), 7.0f);
    wl[k * 130 + o] = (unsigned short)(__float_as_uint(q) >> 16);
  }
  for (int i = t; i < 5 * 130; i += 256) wl[27 * 130 + i] = 0;
  if (t < 128) qbl[t] = rintf(b[t] / s_b);
  for (int i = t; i < 72; i += 256) xl[(i >> 2) * 228 + 224 + (i & 3)] = 0;
  for (int i = t; i < 228; i += 256) xl[18 * 228 + i] = 0;

  #pragma unroll
  for (int sl = 0; sl < 2; ++sl) {
    const int R = blockIdx.x + sl * 1776;
    const int n = R / 222, oh = R - n * 222;
    for (int i = t; i < 9 * 224; i += 256) {
      const int row = i / 224;
      const int col = i - row * 224;
      const int c = row / 3, kh = row - c * 3;
      const float xv = x[((n * 3 + c) * 224 + (oh + kh)) * 224 + col];
      float q = fminf(fmaxf(rintf(xv / s_in), -128.0f), 127.0f);
      xl[(sl * 9 + row) * 228 + col] = (unsigned short)(__float_as_uint(q) >> 16);
    }
  }
  __syncthreads();

  const int lane = t & 63;
  const int wv = t >> 6;
  const int p = lane & 15;
  const int g = lane >> 4;

  // W fragments (B operand): bvw[tt8][j] = w_q[oc=tt8*16+p][k=8g+j]
  bf16x8 bvw[8];
  #pragma unroll
  for (int tt8 = 0; tt8 < 8; ++tt8) {
    ushortx8 u;
    #pragma unroll
    for (int j = 0; j < 8; ++j)
      u[j] = wl[(g * 8 + j) * 130 + tt8 * 16 + p];
    bvw[tt8] = __builtin_bit_cast(bf16x8, u);
  }
  float qbp[8];
  #pragma unroll
  for (int tt8 = 0; tt8 < 8; ++tt8) qbp[tt8] = qbl[tt8 * 16 + p];

  float vmax_local = 0.0f;

  #pragma unroll
  for (int sl = 0; sl < 2; ++sl) {
    int off2[8];
    #pragma unroll
    for (int j = 0; j < 8; ++j) {
      const int k = g * 8 + j;
      int row, kw;
      if (k < 27) {
        const int c = k / 9, rem = k - c * 9;
        const int kh = rem / 3;
        kw = rem - kh * 3;
        row = sl * 9 + c * 3 + kh;
      } else { row = 18; kw = 0; }
      off2[j] = (row * 228 + kw) * 2;
    }

    const int R = blockIdx.x + sl * 1776;
    unsigned short* yrow = y16 + (size_t)R * 28672;   // 128*224 ushorts per row

    #pragma unroll 1
    for (int tt = wv; tt < 14; tt += 4) {
      const int ow0 = tt * 16;
      const char* xbase = (const char*)xl + (ow0 + p) * 2;

      ushortx8 bu;
      #pragma unroll
      for (int j = 0; j < 8; ++j)
        bu[j] = *(const unsigned short*)(xbase + off2[j]);
      const bf16x8 av = __builtin_bit_cast(bf16x8, bu);

      floatx4 acc[8];
      #pragma unroll
      for (int tt8 = 0; tt8 < 8; ++tt8) {
        const float qb = qbp[tt8];
        acc[tt8][0] = qb; acc[tt8][1] = qb; acc[tt8][2] = qb; acc[tt8][3] = qb;
      }
      #pragma unroll
      for (int tt8 = 0; tt8 < 8; ++tt8)
        acc[tt8] = __builtin_amdgcn_mfma_f32_16x16x32_bf16(av, bvw[tt8], acc[tt8], 0, 0, 0);
      // D: ow = ow0 + 4g + r, oc = tt8*16 + p

      #pragma unroll
      for (int tt8 = 0; tt8 < 8; ++tt8) {
        const int a0 = (int)acc[tt8][0], a1 = (int)acc[tt8][1];
        const int a2 = (int)acc[tt8][2], a3 = (int)acc[tt8][3];
        uint2 pk;
        pk.x = ((unsigned)a0 & 0xffffu) | ((unsigned)a1 << 16);
        pk.y = ((unsigned)a2 & 0xffffu) | ((unsigned)a3 << 16);
        *(uint2*)(yrow + (tt8 * 16 + p) * 224 + ow0 + 4 * g) = pk;
        #pragma unroll
        for (int r = 0; r < 4; ++r)
          vmax_local = fmaxf(vmax_local,
              (ow0 + 4 * g + r < 222) ? fabsf(acc[tt8][r]) : 0.0f);
      }
    }
  }

  redf[t] = vmax_local;
  __syncthreads();
  for (int off = 128; off > 0; off >>= 1) {
    if (t < off) redf[t] = fmaxf(redf[t], redf[t + off]);
    __syncthreads();
  }
  if (t == 0) atomicMax(&s[2], __float_as_uint(redf[0]));
}

// streaming finalize: read y16 row (448B/oc, coalesced), quantize, write out (coalesced f32)
__global__ __launch_bounds__(256) void k_final(
    const unsigned short* __restrict__ y16, float* __restrict__ out,
    const unsigned int* __restrict__ s) {
  const float s_in = fmaxf(__uint_as_float(s[0]) / 127.0f, QEPS);
  const float s_w  = fmaxf(__uint_as_float(s[1]) / 7.0f,  QEPS);
  const float s_b  = s_in * s_w;
  const float vmax = __uint_as_float(s[2]);
  const float s_out = fmaxf((s_b * vmax) / 127.0f, QEPS);
  const float h = s_b / s_out;

  const int R = blockIdx.x;
  const int nn = R / 222, ohh = R - nn * 222;
  const int t = threadIdx.x, lane = t & 63, wv = t >> 6;
  const int* srcrow = (const int*)(y16 + (size_t)R * 28672);

  #pragma unroll 1
  for (int oc = wv * 32; oc < wv * 32 + 32; ++oc) {
    const int* src = srcrow + oc * 112;          // dwords: 2 int16 elems each
    float* dst = out + ((size_t)(nn * 128 + oc) * 222 + ohh) * 222;
    if (lane < 56) {
      if ((ohh & 1) == 0) {                      // 16B-aligned row base
        const int2 d = *(const int2*)(src + 2 * lane);   // elems 4L..4L+3
        float f0 = (float)(short)(d.x & 0xffff);
        float f1 = (float)(short)(d.x >> 16);
        float f2 = (float)(short)(d.y & 0xffff);
        float f3 = (float)(short)(d.y >> 16);
        f0 = fminf(fmaxf(rintf(f0 * h), -128.0f), 127.0f) * s_out;
        f1 = fminf(fmaxf(rintf(f1 * h), -128.0f), 127.0f) * s_out;
        f2 = fminf(fmaxf(rintf(f2 * h), -128.0f), 127.0f) * s_out;
        f3 = fminf(fmaxf(rintf(f3 * h), -128.0f), 127.0f) * s_out;
        if (lane < 55) *(float4*)(dst + 4 * lane) = make_float4(f0, f1, f2, f3);
        else           *(float2*)(dst + 220)      = make_float2(f0, f1);
      } else {                                   // base 8 mod 16: 2-elem shift
        if (lane == 0) {
          const int d0 = src[0];
          float f0 = (float)(short)(d0 & 0xffff);
          float f1 = (float)(short)(d0 >> 16);
          f0 = fminf(fmaxf(rintf(f0 * h), -128.0f), 127.0f) * s_out;
          f1 = fminf(fmaxf(rintf(f1 * h), -128.0f), 127.0f) * s_out;
          *(float2*)dst = make_float2(f0, f1);
        } else {
          const int da = src[2 * lane - 1], db = src[2 * lane];  // elems 4L-2..4L+1
          float f0 = (float)(short)(da & 0xffff);
          float f1 = (float)(short)(da >> 16);
          float f2 = (float)(short)(db & 0xffff);
          float f3 = (float)(short)(db >> 16);
          f0 = fminf(fmaxf(rintf(f0 * h), -128.0f), 127.0f) * s_out;
          f1 = fminf(fmaxf(rintf(f1 * h), -128.0f), 127.0f) * s_out;
          f2 = fminf(fmaxf(rintf(f2 * h), -128.0f), 127.0f) * s_out;
          f3 = fminf(fmaxf(rintf(f3 * h), -128.0f), 127.0f) * s_out;
          *(float4*)(dst + 4 * lane - 2) = make_float4(f0, f1, f2, f3);
        }
      }
    }
  }
}

// ================= fallback two-pass path (ws too small) ==============================
#define OFF_XL  8320
#define OFF_QBL 16992
#define OFF_RED 17504
#define OFF_OL  18528
#define SMEM_P0 18528
#define SMEM_P1 47712

template<int PASS>
__global__ __launch_bounds__(256) void k_conv(
    const float* __restrict__ x, const float* __restrict__ W,
    const float* __restrict__ b, float* __restrict__ out,
    unsigned int* __restrict__ s) {
  extern __shared__ __align__(16) char smem[];
  unsigned short* const wl   = (unsigned short*)smem;
  unsigned short* const xl   = (unsigned short*)(smem + OFF_XL);
  float*          const qbl  = (float*)(smem + OFF_QBL);
  float*          const redf = (float*)(smem + OFF_RED);
  unsigned int*   const ol32 = (unsigned int*)(smem + OFF_OL);

  const int t = threadIdx.x;
  const float s_in = fmaxf(__uint_as_float(s[0]) / 127.0f, QEPS);
  const float s_w  = fmaxf(__uint_as_float(s[1]) / 7.0f,  QEPS);
  const float s_b  = s_in * s_w;

  float s_out = 1.0f, h = 1.0f;
  if (PASS == 1) {
    const float vmax = __uint_as_float(s[2]);
    s_out = fmaxf((s_b * vmax) / 127.0f, QEPS);
    h = s_b / s_out;
  }

  for (int i = t; i < 3456; i += 256) {
    const int o = i / 27;
    const int k = i - o * 27;
    float q = rintf(W[i] / s_w);
    q = fminf(fmaxf(q, -7.0f), 7.0f);
    wl[k * 130 + o] = (unsigned short)(__float_as_uint(q) >> 16);
  }
  for (int i = t; i < 5 * 130; i += 256) wl[27 * 130 + i] = 0;
  if (t < 128) qbl[t] = rintf(b[t] / s_b);
  for (int i = t; i < 72; i += 256) xl[(i >> 2) * 228 + 224 + (i & 3)] = 0;
  for (int i = t; i < 228; i += 256) xl[18 * 228 + i] = 0;

  #pragma unroll
  for (int sl = 0; sl < 2; ++sl) {
    const int R = blockIdx.x + sl * 1776;
    const int n = R / 222, oh = R - n * 222;
    for (int i = t; i < 9 * 224; i += 256) {
      const int row = i / 224;
      const int col = i - row * 224;
      const int c = row / 3, kh = row - c * 3;
      const float xv = x[((n * 3 + c) * 224 + (oh + kh)) * 224 + col];
      float q = fminf(fmaxf(rintf(xv / s_in), -128.0f), 127.0f);
      xl[(sl * 9 + row) * 228 + col] = (unsigned short)(__float_as_uint(q) >> 16);
    }
  }
  __syncthreads();

  const int lane = t & 63;
  const int wv = t >> 6;
  const int p = lane & 15;
  const int g = lane >> 4;

  bf16x8 bvw[8];
  #pragma unroll
  for (int tt8 = 0; tt8 < 8; ++tt8) {
    ushortx8 u;
    #pragma unroll
    for (int j = 0; j < 8; ++j)
      u[j] = wl[(g * 8 + j) * 130 + tt8 * 16 + p];
    bvw[tt8] = __builtin_bit_cast(bf16x8, u);
  }
  float qbp[8];
  #pragma unroll
  for (int tt8 = 0; tt8 < 8; ++tt8) qbp[tt8] = qbl[tt8 * 16 + p];

  float vmax_local = 0.0f;

  #pragma unroll
  for (int sl = 0; sl < 2; ++sl) {
    int off2[8];
    #pragma unroll
    for (int j = 0; j < 8; ++j) {
      const int k = g * 8 + j;
      int row, kw;
      if (k < 27) {
        const int c = k / 9, rem = k - c * 9;
        const int kh = rem / 3;
        kw = rem - kh * 3;
        row = sl * 9 + c * 3 + kh;
      } else { row = 18; kw = 0; }
      off2[j] = (row * 228 + kw) * 2;
    }

    const int R = blockIdx.x + sl * 1776;
    const int nn = R / 222, ohh = R - nn * 222;

    #pragma unroll 1
    for (int tt = wv; tt < 14; tt += 4) {
      const int ow0 = tt * 16;
      const char* xbase = (const char*)xl + (ow0 + p) * 2;

      ushortx8 bu;
      #pragma unroll
      for (int j = 0; j < 8; ++j)
        bu[j] = *(const unsigned short*)(xbase + off2[j]);
      const bf16x8 av = __builtin_bit_cast(bf16x8, bu);

      floatx4 acc[8];
      #pragma unroll
      for (int tt8 = 0; tt8 < 8; ++tt8) {
        const float qb = qbp[tt8];
        acc[tt8][0] = qb; acc[tt8][1] = qb; acc[tt8][2] = qb; acc[tt8][3] = qb;
      }
      #pragma unroll
      for (int tt8 = 0; tt8 < 8; ++tt8)
        acc[tt8] = __builtin_amdgcn_mfma_f32_16x16x32_bf16(av, bvw[tt8], acc[tt8], 0, 0, 0);

      if (PASS == 0) {
        #pragma unroll
        for (int tt8 = 0; tt8 < 8; ++tt8)
          #pragma unroll
          for (int r = 0; r < 4; ++r)
            vmax_local = fmaxf(vmax_local,
                (ow0 + 4 * g + r < 222) ? fabsf(acc[tt8][r]) : 0.0f);
      } else {
        #pragma unroll
        for (int tt8 = 0; tt8 < 8; ++tt8) {
          unsigned int pk = 0;
          #pragma unroll
          for (int r = 0; r < 4; ++r) {
            float q = rintf(acc[tt8][r] * h);
            q = fminf(fmaxf(q, -128.0f), 127.0f);
            pk |= ((unsigned int)((int)q & 255)) << (8 * r);
          }
          ol32[(tt8 * 16 + p) * 57 + (ow0 >> 2) + g] = pk;
        }
      }
    }

    if (PASS == 1) {
      __syncthreads();
      #pragma unroll 1
      for (int oc = wv * 32; oc < wv * 32 + 32; ++oc) {
        const unsigned int* src = ol32 + oc * 57;
        float* dst = out + (((nn * 128 + oc) * 222 + ohh) * 222);
        if (lane < 56) {
          const unsigned int bc = src[lane];
          if ((ohh & 1) == 0) {
            float f0 = (float)((int)(bc << 24) >> 24) * s_out;
            float f1 = (float)((int)(bc << 16) >> 24) * s_out;
            float f2 = (float)((int)(bc <<  8) >> 24) * s_out;
            float f3 = (float)((int) bc        >> 24) * s_out;
            if (lane < 55) *(float4*)(dst + 4 * lane) = make_float4(f0, f1, f2, f3);
            else           *(float2*)(dst + 220)      = make_float2(f0, f1);
          } else {
            if (lane == 0) {
              float f0 = (float)((int)(bc << 24) >> 24) * s_out;
              float f1 = (float)((int)(bc << 16) >> 24) * s_out;
              *(float2*)dst = make_float2(f0, f1);
            } else {
              const unsigned int ap = src[lane - 1];
              const unsigned int v = (ap >> 16) | (bc << 16);
              float f0 = (float)((int)(v << 24) >> 24) * s_out;
              float f1 = (float)((int)(v << 16) >> 24) * s_out;
              float f2 = (float)((int)(v <<  8) >> 24) * s_out;
              float f3 = (float)((int) v        >> 24) * s_out;
              *(float4*)(dst + 4 * lane - 2) = make_float4(f0, f1, f2, f3);
            }
          }
        }
      }
      __syncthreads();
    }
  }

  if (PASS == 0) {
    redf[t] = vmax_local;
    __syncthreads();
    for (int off = 128; off > 0; off >>= 1) {
      if (t < off) redf[t] = fmaxf(redf[t], redf[t + off]);
      __syncthreads();
    }
    if (t == 0) atomicMax(&s[2], __float_as_uint(redf[0]));
  }
}

extern "C" void kernel_launch(void* const* d_in, const int* in_sizes, int n_in,
                              void* d_out, int out_size, void* d_ws, size_t ws_size,
                              hipStream_t stream) {
  const float* x = (const float*)d_in[0];
  const float* W = (const float*)d_in[1];
  const float* b = (const float*)d_in[2];
  float* out = (float*)d_out;
  unsigned int* s = (unsigned int*)d_ws;

  k_init<<<1, 64, 0, stream>>>(s);

  const int n4 = in_sizes[0] / 4;  // 602,112
  k_absmax<<<(n4 + 255) / 256, 256, 0, stream>>>(
      (const float4*)x, n4, W, in_sizes[1], s);

  const size_t WS_NEED = 256ull + 3552ull * 57344ull;   // ~203.7 MB
  if (ws_size >= WS_NEED) {
    unsigned short* y16 = (unsigned short*)((char*)d_ws + 256);
    k_conv_ws<<<1776, 256, 0, stream>>>(x, W, b, y16, s);
    k_final<<<3552, 256, 0, stream>>>(y16, out, s);
  } else {
    k_conv<0><<<1776, 256, SMEM_P0, stream>>>(x, W, b, out, s);
    k_conv<1><<<1776, 256, SMEM_P1, stream>>>(x, W, b, out, s);
  }
}

// Round 5
// 560.058 us; speedup vs baseline: 1.1255x; 1.1255x over previous
//
#include <hip/hip_runtime.h>
#include <stdint.h>

#define QEPS 1e-8f

typedef __bf16 bf16x8 __attribute__((ext_vector_type(8)));
typedef unsigned short ushortx8 __attribute__((ext_vector_type(8)));
typedef float floatx4 __attribute__((ext_vector_type(4)));
typedef float floatx2 __attribute__((ext_vector_type(2)));

// s (in d_ws): [0]=absmax bits of x, [1]=absmax bits of W, [2]=absmax of conv accum (quant units)

__global__ void k_init(unsigned int* s) { if (threadIdx.x < 4) s[threadIdx.x] = 0u; }

__global__ __launch_bounds__(256) void k_absmax(
    const float4* __restrict__ x, int n4,
    const float* __restrict__ W, int nw,
    unsigned int* __restrict__ s) {
  __shared__ unsigned int red[256];
  const int t = threadIdx.x;
  unsigned int m = 0u;
  const int i = blockIdx.x * 256 + t;
  if (i < n4) {
    float4 v = x[i];
    m =        __float_as_uint(v.x) & 0x7fffffffu;
    m = max(m, __float_as_uint(v.y) & 0x7fffffffu);
    m = max(m, __float_as_uint(v.z) & 0x7fffffffu);
    m = max(m, __float_as_uint(v.w) & 0x7fffffffu);
  }
  red[t] = m;
  __syncthreads();
  for (int off = 128; off > 0; off >>= 1) {
    if (t < off) red[t] = max(red[t], red[t + off]);
    __syncthreads();
  }
  if (t == 0) atomicMax(&s[0], red[0]);

  if (blockIdx.x == 0) {
    unsigned int mw = 0u;
    for (int j = t; j < nw; j += 256)
      mw = max(mw, __float_as_uint(W[j]) & 0x7fffffffu);
    __syncthreads();
    red[t] = mw;
    __syncthreads();
    for (int off = 128; off > 0; off >>= 1) {
      if (t < off) red[t] = max(red[t], red[t + off]);
      __syncthreads();
    }
    if (t == 0) atomicMax(&s[1], red[0]);
  }
}

// MFMA conv, swapped operands: D = X * W^T per tile -> row(reg)=ow, col(lane&15)=oc.
// Each lane holds 4 CONSECUTIVE ow for one oc => int8-pack to LDS ol[oc][ow],
// then a coalesced writer streams full 888B oc-rows to global (f32, nontemporal).
// LDS carve (bytes): wl 0..8320 | xl 8320..16984 | qbl 16992..17504 |
//                    redf 17504..18528 | ol 18528..47712 (PASS1 only)
#define OFF_XL  8320
#define OFF_QBL 16992
#define OFF_RED 17504
#define OFF_OL  18528
#define SMEM_P0 18528
#define SMEM_P1 47712

template<int PASS>
__global__ __launch_bounds__(256) void k_conv(
    const float* __restrict__ x, const float* __restrict__ W,
    const float* __restrict__ b, float* __restrict__ out,
    unsigned int* __restrict__ s) {
  extern __shared__ __align__(16) char smem[];
  unsigned short* const wl   = (unsigned short*)smem;              // [32 k][130 oc]
  unsigned short* const xl   = (unsigned short*)(smem + OFF_XL);   // [19 row][228 col]
  float*          const qbl  = (float*)(smem + OFF_QBL);           // [128]
  float*          const redf = (float*)(smem + OFF_RED);           // [256]
  unsigned int*   const ol32 = (unsigned int*)(smem + OFF_OL);     // [128 oc][57 dw]

  const int t = threadIdx.x;
  const float s_in = fmaxf(__uint_as_float(s[0]) / 127.0f, QEPS);
  const float s_w  = fmaxf(__uint_as_float(s[1]) / 7.0f,  QEPS);
  const float s_b  = s_in * s_w;

  float s_out = 1.0f, h = 1.0f;
  if (PASS == 1) {
    const float vmax = __uint_as_float(s[2]);
    s_out = fmaxf((s_b * vmax) / 127.0f, QEPS);
    h = s_b / s_out;   // q = rint(v*h): one quant step off worst-case vs per-elem divide
  }

  // ---- stage quantized W (bf16 bits; small ints exact) ----
  for (int i = t; i < 3456; i += 256) {
    const int o = i / 27;
    const int k = i - o * 27;                 // k = c*9 + kh*3 + kw
    float q = rintf(W[i] / s_w);
    q = fminf(fmaxf(q, -7.0f), 7.0f);
    wl[k * 130 + o] = (unsigned short)(__float_as_uint(q) >> 16);
  }
  for (int i = t; i < 5 * 130; i += 256) wl[27 * 130 + i] = 0;  // K-pad rows 27..31
  if (t < 128) qbl[t] = rintf(b[t] / s_b);
  // xl pads: cols 224..227 of rows 0..17, zero-row 18
  for (int i = t; i < 72; i += 256) xl[(i >> 2) * 228 + 224 + (i & 3)] = 0;
  for (int i = t; i < 228; i += 256) xl[18 * 228 + i] = 0;

  // ---- stage quantized x: two (n,oh) slabs ----
  #pragma unroll
  for (int sl = 0; sl < 2; ++sl) {
    const int R = blockIdx.x + sl * 1776;
    const int n = R / 222, oh = R - n * 222;
    for (int i = t; i < 9 * 224; i += 256) {
      const int row = i / 224;                // c*3+kh
      const int col = i - row * 224;
      const int c = row / 3, kh = row - c * 3;
      const float xv = x[((n * 3 + c) * 224 + (oh + kh)) * 224 + col];
      float q = fminf(fmaxf(rintf(xv / s_in), -128.0f), 127.0f);
      xl[(sl * 9 + row) * 228 + col] = (unsigned short)(__float_as_uint(q) >> 16);
    }
  }
  __syncthreads();

  const int lane = t & 63;
  const int wv = t >> 6;
  const int p = lane & 15;        // input-fragment row/col index; D col (oc in tile)
  const int g = lane >> 4;        // k-group: lane holds k = 8g..8g+7

  // W fragments (B operand): bvw[tt8][j] = w_q[oc=tt8*16+p][k=8g+j]
  bf16x8 bvw[8];
  #pragma unroll
  for (int tt8 = 0; tt8 < 8; ++tt8) {
    ushortx8 u;
    #pragma unroll
    for (int j = 0; j < 8; ++j)
      u[j] = wl[(g * 8 + j) * 130 + tt8 * 16 + p];
    bvw[tt8] = __builtin_bit_cast(bf16x8, u);
  }
  // per-lane bias (oc = tt8*16 + p)
  float qbp[8];
  #pragma unroll
  for (int tt8 = 0; tt8 < 8; ++tt8) qbp[tt8] = qbl[tt8 * 16 + p];

  float vmax_local = 0.0f;

  #pragma unroll
  for (int sl = 0; sl < 2; ++sl) {
    // per-lane tap byte-offsets into xl for this slab's 8 K-slots
    int off2[8];
    #pragma unroll
    for (int j = 0; j < 8; ++j) {
      const int k = g * 8 + j;
      int row, kw;
      if (k < 27) {
        const int c = k / 9, rem = k - c * 9;
        const int kh = rem / 3;
        kw = rem - kh * 3;
        row = sl * 9 + c * 3 + kh;
      } else { row = 18; kw = 0; }
      off2[j] = (row * 228 + kw) * 2;
    }

    const int R = blockIdx.x + sl * 1776;
    const int nn = R / 222, ohh = R - nn * 222;

    // ---- conv: 14 ow-tiles round-robin over 4 waves ----
    #pragma unroll 1
    for (int tt = wv; tt < 14; tt += 4) {
      const int ow0 = tt * 16;
      const char* xbase = (const char*)xl + (ow0 + p) * 2;

      ushortx8 bu;
      #pragma unroll
      for (int j = 0; j < 8; ++j)
        bu[j] = *(const unsigned short*)(xbase + off2[j]);
      const bf16x8 av = __builtin_bit_cast(bf16x8, bu);   // A operand: x rows = ow

      floatx4 acc[8];
      #pragma unroll
      for (int tt8 = 0; tt8 < 8; ++tt8) {
        const float qb = qbp[tt8];
        acc[tt8][0] = qb; acc[tt8][1] = qb; acc[tt8][2] = qb; acc[tt8][3] = qb;
      }
      #pragma unroll
      for (int tt8 = 0; tt8 < 8; ++tt8)
        acc[tt8] = __builtin_amdgcn_mfma_f32_16x16x32_bf16(av, bvw[tt8], acc[tt8], 0, 0, 0);
      // D: ow = ow0 + 4g + r, oc = tt8*16 + p

      if (PASS == 0) {
        #pragma unroll
        for (int tt8 = 0; tt8 < 8; ++tt8)
          #pragma unroll
          for (int r = 0; r < 4; ++r)
            vmax_local = fmaxf(vmax_local,
                (ow0 + 4 * g + r < 222) ? fabsf(acc[tt8][r]) : 0.0f);
      } else {
        #pragma unroll
        for (int tt8 = 0; tt8 < 8; ++tt8) {
          unsigned int pk = 0;
          #pragma unroll
          for (int r = 0; r < 4; ++r) {
            float q = rintf(acc[tt8][r] * h);
            q = fminf(fmaxf(q, -128.0f), 127.0f);
            pk |= ((unsigned int)((int)q & 255)) << (8 * r);
          }
          ol32[(tt8 * 16 + p) * 57 + (ow0 >> 2) + g] = pk;  // 4 int8 ow per lane
        }
      }
    }

    if (PASS == 1) {
      __syncthreads();   // conv writes to ol done
      // ---- coalesced writer: wave wv streams oc rows [wv*32, wv*32+32) ----
      #pragma unroll 1
      for (int oc = wv * 32; oc < wv * 32 + 32; ++oc) {
        const unsigned int* src = ol32 + oc * 57;
        float* dst = out + (((nn * 128 + oc) * 222 + ohh) * 222);
        if (lane < 56) {
          const unsigned int bc = src[lane];
          if ((ohh & 1) == 0) {            // row base 16B-aligned
            float f0 = (float)((int)(bc << 24) >> 24) * s_out;
            float f1 = (float)((int)(bc << 16) >> 24) * s_out;
            float f2 = (float)((int)(bc <<  8) >> 24) * s_out;
            float f3 = (float)((int) bc        >> 24) * s_out;
            if (lane < 55) {
              floatx4 v4 = {f0, f1, f2, f3};
              __builtin_nontemporal_store(v4, (floatx4*)(dst + 4 * lane));
            } else {
              floatx2 v2 = {f0, f1};
              __builtin_nontemporal_store(v2, (floatx2*)(dst + 220));
            }
          } else {                         // row base 8 mod 16: shift by 2 elems
            if (lane == 0) {
              float f0 = (float)((int)(bc << 24) >> 24) * s_out;
              float f1 = (float)((int)(bc << 16) >> 24) * s_out;
              floatx2 v2 = {f0, f1};
              __builtin_nontemporal_store(v2, (floatx2*)dst);
            } else {
              const unsigned int ap = src[lane - 1];
              const unsigned int v = (ap >> 16) | (bc << 16);  // elems 4L-2..4L+1
              float f0 = (float)((int)(v << 24) >> 24) * s_out;
              float f1 = (float)((int)(v << 16) >> 24) * s_out;
              float f2 = (float)((int)(v <<  8) >> 24) * s_out;
              float f3 = (float)((int) v        >> 24) * s_out;
              floatx4 v4 = {f0, f1, f2, f3};
              __builtin_nontemporal_store(v4, (floatx4*)(dst + 4 * lane - 2));
            }
          }
        }
      }
      __syncthreads();   // writer reads done before next slab's conv overwrites ol
    }
  }

  if (PASS == 0) {
    redf[t] = vmax_local;
    __syncthreads();
    for (int off = 128; off > 0; off >>= 1) {
      if (t < off) redf[t] = fmaxf(redf[t], redf[t + off]);
      __syncthreads();
    }
    if (t == 0) atomicMax(&s[2], __float_as_uint(redf[0]));
  }
}

extern "C" void kernel_launch(void* const* d_in, const int* in_sizes, int n_in,
                              void* d_out, int out_size, void* d_ws, size_t ws_size,
                              hipStream_t stream) {
  const float* x = (const float*)d_in[0];
  const float* W = (const float*)d_in[1];
  const float* b = (const float*)d_in[2];
  float* out = (float*)d_out;
  unsigned int* s = (unsigned int*)d_ws;

  k_init<<<1, 64, 0, stream>>>(s);

  const int n4 = in_sizes[0] / 4;  // 602,112
  k_absmax<<<(n4 + 255) / 256, 256, 0, stream>>>(
      (const float4*)x, n4, W, in_sizes[1], s);

  k_conv<0><<<1776, 256, SMEM_P0, stream>>>(x, W, b, out, s);
  k_conv<1><<<1776, 256, SMEM_P1, stream>>>(x, W, b, out, s);
}